// Round 1
// baseline (927.534 us; speedup 1.0000x reference)
//
#include <hip/hip_runtime.h>

#define BLOCK 1024
#define NW (BLOCK / 64)
#define DMAX 32000

__global__ void zero_out_kernel(float* out) { out[0] = 0.0f; }

__device__ __forceinline__ float block_sum(float v, float* red) {
    #pragma unroll
    for (int off = 32; off; off >>= 1) v += __shfl_down(v, off, 64);
    const int tid = threadIdx.x;
    if ((tid & 63) == 0) red[tid >> 6] = v;
    __syncthreads();
    float s = red[0];
    #pragma unroll
    for (int w = 1; w < NW; ++w) s += red[w];
    __syncthreads();
    return s;
}

__global__ __launch_bounds__(BLOCK) void tsallis_kernel(
    const float* __restrict__ inp, const int* __restrict__ tgt,
    float* __restrict__ out, int d, float inv_n)
{
    __shared__ float sx[DMAX];      // X * (alpha-1), fp32
    __shared__ float red[NW];

    const int row = blockIdx.x;
    const int tid = threadIdx.x;
    const int d4 = d >> 2;
    const float4* __restrict__ g4 = (const float4*)(inp + (size_t)row * d);
    float4* sx4 = (float4*)sx;

    // ---- load + scale by (alpha-1)=0.5, track max ----
    float lmax = -__builtin_inff();
    for (int i = tid; i < d4; i += BLOCK) {
        float4 v = g4[i];
        v.x *= 0.5f; v.y *= 0.5f; v.z *= 0.5f; v.w *= 0.5f;
        sx4[i] = v;
        lmax = fmaxf(fmaxf(lmax, fmaxf(v.x, v.y)), fmaxf(v.z, v.w));
    }
    #pragma unroll
    for (int off = 32; off; off >>= 1) lmax = fmaxf(lmax, __shfl_down(lmax, off, 64));
    if ((tid & 63) == 0) red[tid >> 6] = lmax;
    __syncthreads();
    float maxv = red[0];
    #pragma unroll
    for (int w = 1; w < NW; ++w) maxv = fmaxf(maxv, red[w]);
    __syncthreads();

    float tau_lo = maxv - 1.0f;
    const float tau_hi = maxv - 0.005590169943749474f;  // (1/32000)^0.5

    // ---- f_lo ----
    float s = 0.0f;
    for (int i = tid; i < d4; i += BLOCK) {
        float4 v = sx4[i];
        float z;
        z = fmaxf(v.x - tau_lo, 0.0f); s = fmaf(z, z, s);
        z = fmaxf(v.y - tau_lo, 0.0f); s = fmaf(z, z, s);
        z = fmaxf(v.z - tau_lo, 0.0f); s = fmaf(z, z, s);
        z = fmaxf(v.w - tau_lo, 0.0f); s = fmaf(z, z, s);
    }
    const float f_lo = block_sum(s, red) - 1.0f;

    // ---- 14 masked bisection updates (15th update is dead code in ref) ----
    float dm = tau_hi - tau_lo;
    for (int it = 0; it < 14; ++it) {
        dm *= 0.5f;
        const float tau_m = tau_lo + dm;
        s = 0.0f;
        for (int i = tid; i < d4; i += BLOCK) {
            float4 v = sx4[i];
            float z;
            z = fmaxf(v.x - tau_m, 0.0f); s = fmaf(z, z, s);
            z = fmaxf(v.y - tau_m, 0.0f); s = fmaf(z, z, s);
            z = fmaxf(v.z - tau_m, 0.0f); s = fmaf(z, z, s);
            z = fmaxf(v.w - tau_m, 0.0f); s = fmaf(z, z, s);
        }
        const float f_m = block_sum(s, red) - 1.0f;
        if (f_m * f_lo >= 0.0f) tau_lo = tau_m;   // uniform across block
    }

    // ---- final eval at tau_m of iteration 15: sum p^1.5 = z^3, sum p*X ----
    dm *= 0.5f;
    const float tau_m = tau_lo + dm;
    float sa = 0.0f, spx = 0.0f;
    for (int i = tid; i < d4; i += BLOCK) {
        float4 v = sx4[i];
        float z, p;
        z = fmaxf(v.x - tau_m, 0.0f); p = z * z; sa = fmaf(p, z, sa); spx = fmaf(p, v.x, spx);
        z = fmaxf(v.y - tau_m, 0.0f); p = z * z; sa = fmaf(p, z, sa); spx = fmaf(p, v.y, spx);
        z = fmaxf(v.z - tau_m, 0.0f); p = z * z; sa = fmaf(p, z, sa); spx = fmaf(p, v.z, spx);
        z = fmaxf(v.w - tau_m, 0.0f); p = z * z; sa = fmaf(p, z, sa); spx = fmaf(p, v.w, spx);
    }
    const float SA  = block_sum(sa, red);
    const float SPX = block_sum(spx, red);

    if (tid == 0) {
        const float xt = sx[tgt[row]];                 // = input[target]*0.5
        // loss = (1 - sum p^a)/(a(a-1)) + dot(p,input) - input[target]
        const float loss = (1.0f - SA) / 0.75f + 2.0f * SPX - 2.0f * xt;
        atomicAdd(out, loss * inv_n);
    }
}

extern "C" void kernel_launch(void* const* d_in, const int* in_sizes, int n_in,
                              void* d_out, int out_size, void* d_ws, size_t ws_size,
                              hipStream_t stream) {
    const float* inp = (const float*)d_in[0];
    const int*   tgt = (const int*)d_in[1];
    float*       out = (float*)d_out;
    const int n = in_sizes[1];            // 4096 rows
    const int d = in_sizes[0] / n;        // 32000

    zero_out_kernel<<<1, 1, 0, stream>>>(out);
    tsallis_kernel<<<n, BLOCK, 0, stream>>>(inp, tgt, out, d, 1.0f / (float)n);
}

// Round 2
// 777.418 us; speedup vs baseline: 1.1931x; 1.1931x over previous
//
#include <hip/hip_runtime.h>

#define BLOCK 1024
#define NW (BLOCK / 64)
#define CAP 6144   // 24 KB LDS compact buffer; expected K ~450 for this data

__global__ void zero_out_kernel(float* out) { out[0] = 0.0f; }

__device__ __forceinline__ float block_sum(float v, float* red) {
    #pragma unroll
    for (int off = 32; off; off >>= 1) v += __shfl_down(v, off, 64);
    const int tid = threadIdx.x;
    if ((tid & 63) == 0) red[tid >> 6] = v;
    __syncthreads();
    float s = 0.0f;
    #pragma unroll
    for (int w = 0; w < NW; ++w) s += red[w];
    __syncthreads();
    return s;
}

__device__ __forceinline__ float block_max(float v, float* red) {
    #pragma unroll
    for (int off = 32; off; off >>= 1) v = fmaxf(v, __shfl_down(v, off, 64));
    const int tid = threadIdx.x;
    if ((tid & 63) == 0) red[tid >> 6] = v;
    __syncthreads();
    float s = red[0];
    #pragma unroll
    for (int w = 1; w < NW; ++w) s = fmaxf(s, red[w]);
    __syncthreads();
    return s;
}

// Elements with x_scaled <= max-1 have p=0 at every tau in [tau_lo, tau_hi]:
// they affect neither the bisection nor the loss. Compact the ~1.4% active
// set once, then bisect on it. __launch_bounds__(1024,8) caps VGPR at 64 ->
// 2 blocks/CU so streaming/bisection phases overlap across blocks.
__global__ __launch_bounds__(BLOCK, 8) void tsallis_kernel(
    const float* __restrict__ inp, const int* __restrict__ tgt,
    float* __restrict__ out, int d, float inv_n)
{
    __shared__ float cbuf[CAP];
    __shared__ float red[NW];
    __shared__ int sK;

    const int row = blockIdx.x;
    const int tid = threadIdx.x;
    const int lane = tid & 63;
    const size_t rb = (size_t)row * (size_t)d;
    const float4* __restrict__ g4 = (const float4*)(inp + rb);
    const int d4 = d >> 2;   // d % 4 == 0 (32000)

    float raw_t = 0.0f;
    if (tid == 0) { sK = 0; raw_t = inp[rb + (size_t)tgt[row]]; }

    // ---- phase 1: row max (raw units; scale by 0.5 afterwards — exact) ----
    float m = -3.4e38f;
    for (int i = tid; i < d4; i += BLOCK) {
        float4 v = g4[i];
        m = fmaxf(fmaxf(m, fmaxf(v.x, v.y)), fmaxf(v.z, v.w));
    }
    const float maxraw = block_max(m, red);  // syncthreads inside covers sK=0
    const float maxv = 0.5f * maxraw;
    // raw > maxraw-2  <=>  0.5*raw > maxv-1  (exact: scaling by 0.5 is lossless)
    const float lo_raw = maxraw - 2.0f;

    // ---- phase 2: compact active elements (scaled) into LDS (reads hit L2/L3) ----
    for (int i = tid; i < d4; i += BLOCK) {
        float4 v = g4[i];
        float vv[4] = {v.x, v.y, v.z, v.w};
        #pragma unroll
        for (int j = 0; j < 4; ++j) {
            const bool pred = vv[j] > lo_raw;
            const unsigned long long mask = __ballot(pred);
            if (mask) {
                const int leader = __ffsll(mask) - 1;
                int base = 0;
                if (lane == leader) base = atomicAdd(&sK, __popcll(mask));
                base = __shfl(base, leader, 64);
                if (pred) {
                    const int p = base + __popcll(mask & ((1ull << (unsigned)lane) - 1ull));
                    if (p < CAP) cbuf[p] = 0.5f * vv[j];
                }
            }
        }
    }
    __syncthreads();
    const int K = sK;

    float tau_lo = maxv - 1.0f;
    const float tau_hi = maxv - sqrtf(1.0f / (float)d);
    float dm = tau_hi - tau_lo;
    float SA, SPX;

    if (K <= BLOCK) {
        // hot path: one active value per thread, bisection = 15 block reductions
        const float hv = (tid < K) ? cbuf[tid] : -1.0e30f;  // inactive -> z=0, p=0
        float z = fmaxf(hv - tau_lo, 0.0f);
        const float f_lo = block_sum(z * z, red) - 1.0f;
        #pragma unroll 1
        for (int it = 0; it < 14; ++it) {   // 15th mask update is dead code in ref
            dm *= 0.5f;
            const float tm = tau_lo + dm;
            z = fmaxf(hv - tm, 0.0f);
            const float f_m = block_sum(z * z, red) - 1.0f;
            if (f_m * f_lo >= 0.0f) tau_lo = tm;
        }
        dm *= 0.5f;
        const float tm = tau_lo + dm;
        z = fmaxf(hv - tm, 0.0f);
        const float p = z * z;
        SA  = block_sum(p * z, red);    // sum p^1.5
        SPX = block_sum(p * hv, red);   // sum p * x_scaled
    } else if (K <= CAP) {
        float s = 0.0f;
        for (int idx = tid; idx < K; idx += BLOCK) { float z = fmaxf(cbuf[idx] - tau_lo, 0.0f); s = fmaf(z, z, s); }
        const float f_lo = block_sum(s, red) - 1.0f;
        #pragma unroll 1
        for (int it = 0; it < 14; ++it) {
            dm *= 0.5f;
            const float tm = tau_lo + dm;
            s = 0.0f;
            for (int idx = tid; idx < K; idx += BLOCK) { float z = fmaxf(cbuf[idx] - tm, 0.0f); s = fmaf(z, z, s); }
            const float f_m = block_sum(s, red) - 1.0f;
            if (f_m * f_lo >= 0.0f) tau_lo = tm;
        }
        dm *= 0.5f;
        const float tm = tau_lo + dm;
        float sa = 0.0f, spx = 0.0f;
        for (int idx = tid; idx < K; idx += BLOCK) {
            const float v = cbuf[idx];
            const float z = fmaxf(v - tm, 0.0f); const float p = z * z;
            sa = fmaf(p, z, sa); spx = fmaf(p, v, spx);
        }
        SA = block_sum(sa, red); SPX = block_sum(spx, red);
    } else {
        // overflow fallback (never taken for Gaussian data): stream from global
        float s = 0.0f;
        for (int i = tid; i < d4; i += BLOCK) {
            float4 v = g4[i];
            float z;
            z = fmaxf(0.5f * v.x - tau_lo, 0.0f); s = fmaf(z, z, s);
            z = fmaxf(0.5f * v.y - tau_lo, 0.0f); s = fmaf(z, z, s);
            z = fmaxf(0.5f * v.z - tau_lo, 0.0f); s = fmaf(z, z, s);
            z = fmaxf(0.5f * v.w - tau_lo, 0.0f); s = fmaf(z, z, s);
        }
        const float f_lo = block_sum(s, red) - 1.0f;
        #pragma unroll 1
        for (int it = 0; it < 14; ++it) {
            dm *= 0.5f;
            const float tm = tau_lo + dm;
            s = 0.0f;
            for (int i = tid; i < d4; i += BLOCK) {
                float4 v = g4[i];
                float z;
                z = fmaxf(0.5f * v.x - tm, 0.0f); s = fmaf(z, z, s);
                z = fmaxf(0.5f * v.y - tm, 0.0f); s = fmaf(z, z, s);
                z = fmaxf(0.5f * v.z - tm, 0.0f); s = fmaf(z, z, s);
                z = fmaxf(0.5f * v.w - tm, 0.0f); s = fmaf(z, z, s);
            }
            const float f_m = block_sum(s, red) - 1.0f;
            if (f_m * f_lo >= 0.0f) tau_lo = tm;
        }
        dm *= 0.5f;
        const float tm = tau_lo + dm;
        float sa = 0.0f, spx = 0.0f;
        for (int i = tid; i < d4; i += BLOCK) {
            float4 v = g4[i];
            float vv[4] = {0.5f * v.x, 0.5f * v.y, 0.5f * v.z, 0.5f * v.w};
            #pragma unroll
            for (int j = 0; j < 4; ++j) {
                const float z = fmaxf(vv[j] - tm, 0.0f); const float p = z * z;
                sa = fmaf(p, z, sa); spx = fmaf(p, vv[j], spx);
            }
        }
        SA = block_sum(sa, red); SPX = block_sum(spx, red);
    }

    if (tid == 0) {
        // loss = (1 - sum p^a)/(a(a-1)) + 2*sum(p*x_scaled) - input[target]
        const float loss = (1.0f - SA) * (1.0f / 0.75f) + 2.0f * SPX - raw_t;
        atomicAdd(out, loss * inv_n);
    }
}

extern "C" void kernel_launch(void* const* d_in, const int* in_sizes, int n_in,
                              void* d_out, int out_size, void* d_ws, size_t ws_size,
                              hipStream_t stream) {
    const float* inp = (const float*)d_in[0];
    const int*   tgt = (const int*)d_in[1];
    float*       out = (float*)d_out;
    const int n = in_sizes[1];            // 4096 rows
    const int d = in_sizes[0] / n;        // 32000

    zero_out_kernel<<<1, 1, 0, stream>>>(out);
    tsallis_kernel<<<n, BLOCK, 0, stream>>>(inp, tgt, out, d, 1.0f / (float)n);
}

// Round 3
// 739.850 us; speedup vs baseline: 1.2537x; 1.0508x over previous
//
#include <hip/hip_runtime.h>

#define BLOCK 512
#define NW (BLOCK / 64)
#define CAP 8192      // 32 KB superset buffer (expect ~2.4K for this data)
#define FCAP 1024     // 4 KB exact-active buffer (expect ~450)

__global__ void zero_out_kernel(float* out) { out[0] = 0.0f; }

__device__ __forceinline__ float block_sum(float v, float* red) {
    #pragma unroll
    for (int off = 32; off; off >>= 1) v += __shfl_down(v, off, 64);
    const int tid = threadIdx.x;
    if ((tid & 63) == 0) red[tid >> 6] = v;
    __syncthreads();
    float s = 0.0f;
    #pragma unroll
    for (int w = 0; w < NW; ++w) s += red[w];
    __syncthreads();
    return s;
}

__device__ __forceinline__ float block_max(float v, float* red) {
    #pragma unroll
    for (int off = 32; off; off >>= 1) v = fmaxf(v, __shfl_down(v, off, 64));
    const int tid = threadIdx.x;
    if ((tid & 63) == 0) red[tid >> 6] = v;
    __syncthreads();
    float s = red[0];
    #pragma unroll
    for (int w = 1; w < NW; ++w) s = fmaxf(s, red[w]);
    __syncthreads();
    return s;
}

__device__ __forceinline__ float wave_sum(float v) {
    #pragma unroll
    for (int off = 32; off; off >>= 1) v += __shfl_xor(v, off, 64);
    return v;  // all lanes hold the sum
}

// Redundant per-wave bisection: every wave computes the identical result from
// NR registers/lane — no barriers, no LDS in the serial phase.
template <int NR>
__device__ __forceinline__ void wave_bisect(const float* __restrict__ fbuf, int K,
                                            float tau_lo, float dm, int lane,
                                            float& SA, float& SPX) {
    float hv[NR];
    #pragma unroll
    for (int j = 0; j < NR; ++j) {
        const int idx = lane + (j << 6);
        hv[j] = (idx < K) ? fbuf[idx] : -1.0e30f;   // pad -> z=0, p=0
    }
    float s = 0.0f;
    #pragma unroll
    for (int j = 0; j < NR; ++j) { float z = fmaxf(hv[j] - tau_lo, 0.0f); s = fmaf(z, z, s); }
    const float f_lo = wave_sum(s) - 1.0f;
    #pragma unroll 1
    for (int it = 0; it < 14; ++it) {               // 15th mask update is dead code in ref
        dm *= 0.5f;
        const float tm = tau_lo + dm;
        s = 0.0f;
        #pragma unroll
        for (int j = 0; j < NR; ++j) { float z = fmaxf(hv[j] - tm, 0.0f); s = fmaf(z, z, s); }
        const float f_m = wave_sum(s) - 1.0f;
        if (f_m * f_lo >= 0.0f) tau_lo = tm;        // identical across lanes/waves
    }
    dm *= 0.5f;
    const float tm = tau_lo + dm;
    float sa = 0.0f, spx = 0.0f;
    #pragma unroll
    for (int j = 0; j < NR; ++j) {
        const float z = fmaxf(hv[j] - tm, 0.0f); const float p = z * z;
        sa = fmaf(p, z, sa); spx = fmaf(p, hv[j], spx);
    }
    SA = wave_sum(sa); SPX = wave_sum(spx);
}

__global__ __launch_bounds__(BLOCK, 8) void tsallis_kernel(
    const float* __restrict__ inp, const int* __restrict__ tgt,
    float* __restrict__ out, int d, float inv_n)
{
    __shared__ float sbuf[CAP];    // superset, raw units
    __shared__ float fbuf[FCAP];   // exact active set, scaled (x*0.5)
    __shared__ float red[NW];
    __shared__ int sK, sKf;

    const int row = blockIdx.x;
    const int tid = threadIdx.x;
    const int lane = tid & 63;
    const size_t rb = (size_t)row * (size_t)d;
    const float4* __restrict__ g4 = (const float4*)(inp + rb);
    const int d4 = d >> 2;                  // d % 4 == 0

    float raw_t = 0.0f;
    if (tid == 0) { sK = 0; sKf = 0; raw_t = inp[rb + (size_t)tgt[row]]; }

    // ---- phase 0: sample max over first min(d4,BLOCK) float4s (8 KB, coalesced).
    // Any lower bound on the true max gives a conservative superset threshold.
    float m = -3.4e38f;
    if (tid < d4) {
        float4 v = g4[tid];
        m = fmaxf(fmaxf(v.x, v.y), fmaxf(v.z, v.w));
    }
    const float thr = block_max(m, red) - 2.0f;   // raw units; barrier covers sK/sKf init

    // ---- phase 1: single streaming pass — true max + superset compaction ----
    m = -3.4e38f;
    const int iters = (d4 + BLOCK - 1) / BLOCK;
    for (int t = 0; t < iters; ++t) {
        const int i = tid + t * BLOCK;
        const bool inb = i < d4;
        float4 v;
        if (inb) v = g4[i]; else { v.x = v.y = v.z = v.w = -3.4e38f; }
        m = fmaxf(fmaxf(m, fmaxf(v.x, v.y)), fmaxf(v.z, v.w));
        const float vv[4] = {v.x, v.y, v.z, v.w};
        #pragma unroll
        for (int j = 0; j < 4; ++j) {
            const bool pred = vv[j] > thr;          // whole wave participates (uniform loop)
            const unsigned long long mask = __ballot(pred);
            if (mask) {
                const int leader = __ffsll((long long)mask) - 1;
                int base = 0;
                if (lane == leader) base = atomicAdd(&sK, __popcll(mask));
                base = __shfl(base, leader, 64);
                if (pred) {
                    const int p = base + __popcll(mask & ((1ull << (unsigned)lane) - 1ull));
                    if (p < CAP) sbuf[p] = vv[j];
                }
            }
        }
    }
    const float maxraw = block_max(m, red);       // barrier: sbuf/sK visible after
    const float maxv = 0.5f * maxraw;             // exact scaling
    const int Ksup = sK;

    float tau_lo = maxv - 1.0f;
    const float tau_hi = maxv - sqrtf(1.0f / (float)d);
    const float dm0 = tau_hi - tau_lo;
    float SA, SPX;

    if (Ksup <= CAP) {
        // ---- phase 2: exact filter (raw > maxraw-2  <=>  p>0 possible) ----
        const float fthr = maxraw - 2.0f;
        const int fiters = (Ksup + BLOCK - 1) / BLOCK;
        for (int t = 0; t < fiters; ++t) {
            const int i = tid + t * BLOCK;
            const bool inb = i < Ksup;
            const float v = inb ? sbuf[i] : -3.4e38f;
            const bool pred = inb && (v > fthr);
            const unsigned long long mask = __ballot(pred);
            if (mask) {
                const int leader = __ffsll((long long)mask) - 1;
                int base = 0;
                if (lane == leader) base = atomicAdd(&sKf, __popcll(mask));
                base = __shfl(base, leader, 64);
                if (pred) {
                    const int p = base + __popcll(mask & ((1ull << (unsigned)lane) - 1ull));
                    if (p < FCAP) fbuf[p] = 0.5f * v;   // store scaled
                }
            }
        }
        __syncthreads();
        const int K = sKf;

        if (K <= 512) {
            wave_bisect<8>(fbuf, K, tau_lo, dm0, lane, SA, SPX);
        } else if (K <= FCAP) {
            wave_bisect<16>(fbuf, K, tau_lo, dm0, lane, SA, SPX);
        } else {
            // block path over the superset (extras contribute exactly 0)
            float dm = dm0;
            float s = 0.0f;
            for (int i = tid; i < Ksup; i += BLOCK) { float z = fmaxf(0.5f * sbuf[i] - tau_lo, 0.0f); s = fmaf(z, z, s); }
            const float f_lo = block_sum(s, red) - 1.0f;
            #pragma unroll 1
            for (int it = 0; it < 14; ++it) {
                dm *= 0.5f;
                const float tm = tau_lo + dm;
                s = 0.0f;
                for (int i = tid; i < Ksup; i += BLOCK) { float z = fmaxf(0.5f * sbuf[i] - tm, 0.0f); s = fmaf(z, z, s); }
                const float f_m = block_sum(s, red) - 1.0f;
                if (f_m * f_lo >= 0.0f) tau_lo = tm;
            }
            dm *= 0.5f;
            const float tm = tau_lo + dm;
            float sa = 0.0f, spx = 0.0f;
            for (int i = tid; i < Ksup; i += BLOCK) {
                const float v = 0.5f * sbuf[i];
                const float z = fmaxf(v - tm, 0.0f); const float p = z * z;
                sa = fmaf(p, z, sa); spx = fmaf(p, v, spx);
            }
            SA = block_sum(sa, red); SPX = block_sum(spx, red);
        }
    } else {
        // ---- overflow fallback: stream from global (never taken for this data) ----
        float dm = dm0;
        float s = 0.0f;
        for (int i = tid; i < d4; i += BLOCK) {
            float4 v = g4[i];
            float z;
            z = fmaxf(0.5f * v.x - tau_lo, 0.0f); s = fmaf(z, z, s);
            z = fmaxf(0.5f * v.y - tau_lo, 0.0f); s = fmaf(z, z, s);
            z = fmaxf(0.5f * v.z - tau_lo, 0.0f); s = fmaf(z, z, s);
            z = fmaxf(0.5f * v.w - tau_lo, 0.0f); s = fmaf(z, z, s);
        }
        const float f_lo = block_sum(s, red) - 1.0f;
        #pragma unroll 1
        for (int it = 0; it < 14; ++it) {
            dm *= 0.5f;
            const float tm = tau_lo + dm;
            s = 0.0f;
            for (int i = tid; i < d4; i += BLOCK) {
                float4 v = g4[i];
                float z;
                z = fmaxf(0.5f * v.x - tm, 0.0f); s = fmaf(z, z, s);
                z = fmaxf(0.5f * v.y - tm, 0.0f); s = fmaf(z, z, s);
                z = fmaxf(0.5f * v.z - tm, 0.0f); s = fmaf(z, z, s);
                z = fmaxf(0.5f * v.w - tm, 0.0f); s = fmaf(z, z, s);
            }
            const float f_m = block_sum(s, red) - 1.0f;
            if (f_m * f_lo >= 0.0f) tau_lo = tm;
        }
        dm *= 0.5f;
        const float tm = tau_lo + dm;
        float sa = 0.0f, spx = 0.0f;
        for (int i = tid; i < d4; i += BLOCK) {
            float4 v = g4[i];
            const float vv[4] = {0.5f * v.x, 0.5f * v.y, 0.5f * v.z, 0.5f * v.w};
            #pragma unroll
            for (int j = 0; j < 4; ++j) {
                const float z = fmaxf(vv[j] - tm, 0.0f); const float p = z * z;
                sa = fmaf(p, z, sa); spx = fmaf(p, vv[j], spx);
            }
        }
        SA = block_sum(sa, red); SPX = block_sum(spx, red);
    }

    if (tid == 0) {
        // loss = (1 - sum p^a)/(a(a-1)) + 2*sum(p*x_scaled) - input[target]
        const float loss = (1.0f - SA) * (1.0f / 0.75f) + 2.0f * SPX - raw_t;
        atomicAdd(out, loss * inv_n);
    }
}

extern "C" void kernel_launch(void* const* d_in, const int* in_sizes, int n_in,
                              void* d_out, int out_size, void* d_ws, size_t ws_size,
                              hipStream_t stream) {
    const float* inp = (const float*)d_in[0];
    const int*   tgt = (const int*)d_in[1];
    float*       out = (float*)d_out;
    const int n = in_sizes[1];            // 4096 rows
    const int d = in_sizes[0] / n;        // 32000

    zero_out_kernel<<<1, 1, 0, stream>>>(out);
    tsallis_kernel<<<n, BLOCK, 0, stream>>>(inp, tgt, out, d, 1.0f / (float)n);
}